// Round 5
// baseline (486.158 us; speedup 1.0000x reference)
//
#include <hip/hip_runtime.h>

typedef unsigned int uint32;

__device__ __forceinline__ float fexp2(float x) { return __builtin_amdgcn_exp2f(x); }
__device__ __forceinline__ float flog2(float x) { return __builtin_amdgcn_logf(x); }

__device__ __forceinline__ float s2lin(float c) {
    float p = fexp2(flog2((c + 0.055f) * (1.0f / 1.055f)) * 2.4f);
    return c > 0.04045f ? p : c * (1.0f / 12.92f);
}

__device__ __forceinline__ float labf(float t) {
    float p = fexp2(flog2(t) * (1.0f / 3.0f));
    return t > 0.008856f ? p : 7.787f * t + (16.0f / 116.0f);
}

__device__ __forceinline__ void px(float r, float g, float b,
                                   float& L, float& a01, float& b01) {
    float lr = s2lin(r), lg = s2lin(g), lb = s2lin(b);
    // RGB2XYZ rows pre-divided by D65 white (0.95047, 1.0, 1.08883)
    float X = 0.43395300f * lr + 0.37621900f * lg + 0.18982460f * lb;
    float Y = 0.21267100f * lr + 0.71516000f * lg + 0.07216900f * lb;
    float Z = 0.01775660f * lr + 0.10946970f * lg + 0.87270740f * lb;
    float fx = labf(X), fy = labf(Y), fz = labf(Z);
    L   = 116.0f * fy - 16.0f;                              // L in [0,100]
    a01 = (500.0f * (fx - fy) + 128.0f) * (1.0f / 255.0f);
    b01 = (200.0f * (fy - fz) + 128.0f) * (1.0f / 255.0f);
}

__device__ __forceinline__ uint32 packpx(float L, float a01, float b01) {
    uint32 au = (uint32)(a01 * 255.0f + 0.5f);
    uint32 bu = (uint32)(b01 * 255.0f + 0.5f);
    unsigned short hb = __builtin_bit_cast(unsigned short, (_Float16)L);
    return au | (bu << 8) | ((uint32)hb << 16);
}

// chunk of 4 px in 3 float4: {r0,g0,b0,r1},{g1,b1,r2,g2},{b2,r3,g3,b3}
__device__ __forceinline__ void chunk_pack(const float4& A, const float4& B,
                                           const float4& C, uint32* pk,
                                           float& m1, float& m2) {
    float L, a, b;
    px(A.x, A.y, A.z, L, a, b); m1 = fminf(m1, L); m2 = fminf(m2, 100.0f - L); pk[0] = packpx(L, a, b);
    px(A.w, B.x, B.y, L, a, b); m1 = fminf(m1, L); m2 = fminf(m2, 100.0f - L); pk[1] = packpx(L, a, b);
    px(B.z, B.w, C.x, L, a, b); m1 = fminf(m1, L); m2 = fminf(m2, 100.0f - L); pk[2] = packpx(L, a, b);
    px(C.y, C.z, C.w, L, a, b); m1 = fminf(m1, L); m2 = fminf(m2, 100.0f - L); pk[3] = packpx(L, a, b);
}

// ws layout (u32 units):
//   [0, 1024)        per-image arrival counters (512 used) -- zeroed by memsetAsync
//   [1024, 5120)     partial mins: (img*4+sub)*2 -> {min L, min(100-L)} as f32
//   [8192, ...)      packed px: img*16384 + sub*4096 + 4*(256*c + t) + i
#define WS_PX_OFF 8192

// 2048 blocks x 256 threads, 4 blocks per image. Each block: compute+pack its
// quarter to ws, publish partial min, threadfence + atomicAdd(counter). First
// three blocks EXIT (no spin -> no deadlock, dispatch-order-safe). The last
// block (old==3) acquires, reads the 4 min-pairs + 64 KB packed (L2/L3-hot),
// rescales, writes the image's 192 KB output. Phase-2 of image i overlaps
// phase-1 of other images -> no convoy. No forced launch bounds (R2/R4: forcing
// min-waves caused 32-VGPR scratch spills).
__global__ __launch_bounds__(256) void k_fin(const float* __restrict__ x,
                                             float* __restrict__ out,
                                             uint32* __restrict__ ws) {
    const int bid = blockIdx.x, t = threadIdx.x;
    const int img = bid >> 2, sub = bid & 3;
    const size_t base4 = (size_t)img * 12288 + (size_t)sub * 3072;
    const float4* __restrict__ in4 = (const float4*)x + base4;

    uint32 pk[16];
    float m1 = 3.4e38f, m2 = 3.4e38f;            // min(L), min(100-L)

    // software pipeline: chunk c+1 loads in flight during chunk c compute
    float4 A = in4[3 * t], B = in4[3 * t + 1], C = in4[3 * t + 2];
#pragma unroll
    for (int c = 0; c < 4; ++c) {
        float4 An, Bn, Cn;
        if (c < 3) {
            const int o = (c + 1) * 768 + 3 * t;
            An = in4[o]; Bn = in4[o + 1]; Cn = in4[o + 2];
        }
        chunk_pack(A, B, C, &pk[4 * c], m1, m2);
        A = An; B = Bn; C = Cn;
    }

    // store packed quarter: uint4 per chunk, coalesced 16 B/lane
    uint4* __restrict__ wp4 =
        (uint4*)(ws + WS_PX_OFF + (size_t)img * 16384 + (size_t)sub * 4096);
#pragma unroll
    for (int c = 0; c < 4; ++c)
        wp4[256 * c + t] = make_uint4(pk[4 * c], pk[4 * c + 1],
                                      pk[4 * c + 2], pk[4 * c + 3]);

    // wave reduce then 4-wave LDS reduce
#pragma unroll
    for (int m = 32; m; m >>= 1) {
        m1 = fminf(m1, __shfl_xor(m1, m, 64));
        m2 = fminf(m2, __shfl_xor(m2, m, 64));
    }
    __shared__ float sm[8];
    __shared__ uint32 arrival;
    if ((t & 63) == 0) { sm[(t >> 6) * 2] = m1; sm[(t >> 6) * 2 + 1] = m2; }
    __syncthreads();
    if (t == 0) {
        float* hdr = (float*)(ws + 1024) + ((size_t)img * 4 + sub) * 2;
        hdr[0] = fminf(fminf(sm[0], sm[2]), fminf(sm[4], sm[6]));
        hdr[1] = fminf(fminf(sm[1], sm[3]), fminf(sm[5], sm[7]));
        __threadfence();                          // release: px + mins visible
        arrival = atomicAdd(ws + img, 1u);        // device-scope
        __threadfence();                          // acquire (for finisher path)
    }
    __syncthreads();
    if (arrival != 3u) return;                    // not last: exit, free the CU

    // ---- finisher: whole-image rescale + store ----
    const float* hdr = (const float*)(ws + 1024) + (size_t)img * 8;
    const float Lmin = fminf(fminf(hdr[0], hdr[2]), fminf(hdr[4], hdr[6]));
    const float M2   = fminf(fminf(hdr[1], hdr[3]), fminf(hdr[5], hdr[7]));
    const float s = 1.0f / ((100.0f - M2) - Lmin);

    const uint4* __restrict__ rp4 = (const uint4*)(ws + WS_PX_OFF + (size_t)img * 16384);
    float4* __restrict__ o4 = (float4*)out + (size_t)img * 12288;
#pragma unroll
    for (int g = 0; g < 16; ++g) {
        const uint4 v = rp4[t + 256 * g];         // 4 px, L2/L3-hot
        float L[4], a[4], b[4];
        const uint32 w[4] = {v.x, v.y, v.z, v.w};
#pragma unroll
        for (int i = 0; i < 4; ++i) {
            a[i] = (float)(w[i] & 255u) * (1.0f / 255.0f);
            b[i] = (float)((w[i] >> 8) & 255u) * (1.0f / 255.0f);
            L[i] = ((float)__builtin_bit_cast(_Float16, (unsigned short)(w[i] >> 16)) - Lmin) * s;
        }
        const int o = 3 * (t + 256 * g);
        o4[o]     = make_float4(L[0], a[0], b[0], L[1]);
        o4[o + 1] = make_float4(a[1], b[1], L[2], a[2]);
        o4[o + 2] = make_float4(b[2], L[3], a[3], b[3]);
    }
}

// ---- fallback: round-1 fused kernel (verified) if ws too small ----
__global__ __launch_bounds__(1024) void k_fb(const float* __restrict__ x,
                                             float* __restrict__ out) {
    const int img = blockIdx.x, t = threadIdx.x;
    const size_t base = (size_t)img * 49152;
    const float* __restrict__ in = x + base;
    float* __restrict__ o = out + base;

    uint32 pk[16];
    float m1 = 3.4e38f, m2 = 3.4e38f;
#pragma unroll
    for (int i = 0; i < 16; ++i) {
        const int p = t + (i << 10);
        const float* q = in + 3 * p;
        float L, a01, b01;
        px(q[0], q[1], q[2], L, a01, b01);
        m1 = fminf(m1, L);
        m2 = fminf(m2, 100.0f - L);
        pk[i] = packpx(L, a01, b01);
    }
#pragma unroll
    for (int m = 32; m; m >>= 1) {
        m1 = fminf(m1, __shfl_xor(m1, m, 64));
        m2 = fminf(m2, __shfl_xor(m2, m, 64));
    }
    __shared__ float sm[32];
    if ((t & 63) == 0) { sm[(t >> 6) * 2] = m1; sm[(t >> 6) * 2 + 1] = m2; }
    __syncthreads();
    float Lmin = 3.4e38f, M2 = 3.4e38f;
#pragma unroll
    for (int i = 0; i < 16; ++i) {
        Lmin = fminf(Lmin, sm[2 * i]);
        M2   = fminf(M2,   sm[2 * i + 1]);
    }
    const float s = 1.0f / ((100.0f - M2) - Lmin);
#pragma unroll
    for (int i = 0; i < 16; ++i) {
        const int p = t + (i << 10);
        const uint32 v = pk[i];
        float* q = o + 3 * p;
        q[0] = ((float)__builtin_bit_cast(_Float16, (unsigned short)(v >> 16)) - Lmin) * s;
        q[1] = (float)(v & 255u) * (1.0f / 255.0f);
        q[2] = (float)((v >> 8) & 255u) * (1.0f / 255.0f);
    }
}

extern "C" void kernel_launch(void* const* d_in, const int* in_sizes, int n_in,
                              void* d_out, int out_size, void* d_ws, size_t ws_size,
                              hipStream_t stream) {
    (void)in_sizes; (void)n_in; (void)out_size;
    const float* x = (const float*)d_in[0];
    float* out = (float*)d_out;
    const size_t need = (size_t)WS_PX_OFF * 4 + 512ull * 16384ull * 4ull;
    if (ws_size >= need) {
        hipMemsetAsync(d_ws, 0, 4096, stream);    // zero arrival counters (capture-safe)
        k_fin<<<2048, 256, 0, stream>>>(x, out, (uint32*)d_ws);
    } else {
        k_fb<<<512, 1024, 0, stream>>>(x, out);
    }
}

// Round 6
// 189.957 us; speedup vs baseline: 2.5593x; 2.5593x over previous
//
#include <hip/hip_runtime.h>

typedef unsigned int uint32;

__device__ __forceinline__ float fexp2(float x) { return __builtin_amdgcn_exp2f(x); }
__device__ __forceinline__ float flog2(float x) { return __builtin_amdgcn_logf(x); }

__device__ __forceinline__ float s2lin(float c) {
    float p = fexp2(flog2((c + 0.055f) * (1.0f / 1.055f)) * 2.4f);
    return c > 0.04045f ? p : c * (1.0f / 12.92f);
}

__device__ __forceinline__ float labf(float t) {
    float p = fexp2(flog2(t) * (1.0f / 3.0f));
    return t > 0.008856f ? p : 7.787f * t + (16.0f / 116.0f);
}

__device__ __forceinline__ void px(float r, float g, float b,
                                   float& L, float& a01, float& b01) {
    float lr = s2lin(r), lg = s2lin(g), lb = s2lin(b);
    // RGB2XYZ rows pre-divided by D65 white (0.95047, 1.0, 1.08883)
    float X = 0.43395300f * lr + 0.37621900f * lg + 0.18982460f * lb;
    float Y = 0.21267100f * lr + 0.71516000f * lg + 0.07216900f * lb;
    float Z = 0.01775660f * lr + 0.10946970f * lg + 0.87270740f * lb;
    float fx = labf(X), fy = labf(Y), fz = labf(Z);
    L   = 116.0f * fy - 16.0f;                              // L in [0,100]
    a01 = (500.0f * (fx - fy) + 128.0f) * (1.0f / 255.0f);
    b01 = (200.0f * (fy - fz) + 128.0f) * (1.0f / 255.0f);
}

__device__ __forceinline__ uint32 packpx(float L, float a01, float b01) {
    uint32 au = (uint32)(a01 * 255.0f + 0.5f);
    uint32 bu = (uint32)(b01 * 255.0f + 0.5f);
    unsigned short hb = __builtin_bit_cast(unsigned short, (_Float16)L);
    return au | (bu << 8) | ((uint32)hb << 16);
}

typedef __attribute__((address_space(1))) const void gconst_void;
typedef __attribute__((address_space(3))) void lds_void;

// async global->LDS, 16 B per lane, zero VGPR cost for outstanding data.
// lds dest is wave-uniform base (HW adds lane*16); global src is per-lane.
__device__ __forceinline__ void gload16(const void* g, void* l) {
    __builtin_amdgcn_global_load_lds((gconst_void*)g, (lds_void*)l, 16, 0, 0);
}

#define IMG_BYTES 196608   // 16384 px * 12 B
#define QTR_BYTES 49152    // image quarter (4096 px)

__device__ __forceinline__ void do_quarter(const float* __restrict__ sf, int t, int q,
                                           uint32* pk, float& m1, float& m2) {
#pragma unroll
    for (int i = 0; i < 4; ++i) {
        const int p = t + (i << 10);           // px within quarter
        float L, a01, b01;
        // lane-stride 12 B in LDS -> 2 lanes/bank, conflict-free
        px(sf[3 * p], sf[3 * p + 1], sf[3 * p + 2], L, a01, b01);
        m1 = fminf(m1, L); m2 = fminf(m2, 100.0f - L);
        pk[(q << 2) + i] = packpx(L, a01, b01);
    }
}

// One block per image. RGB staged via global_load_lds into 3 x 48 KB LDS slots
// (dynamic, 144 KB -> 1 block/CU, 16 waves): 9 x 1KB async ops per wave in
// flight = ~144 KB/CU outstanding, vs ~5 KB needed to saturate HBM -- breaks
// the 2.2 TB/s register-starved-MLP plateau of R0/R1/R3. Only per-thread state
// is pk[16] (verified u8 a|u8 b|f16 L encoding), ~48 VGPR, no spill risk.
// Schedule: issue q0-2 | sync | C0 | sync | issue q3->slot0 | C1 C2 (overlap
// q3 staging) | sync | C3 | reduce | rescale+store.
__global__ __launch_bounds__(1024) void k_gl(const float* __restrict__ x,
                                             float* __restrict__ out) {
    extern __shared__ char stage[];            // 3 * QTR_BYTES
    __shared__ float sm[32];
    const int t = threadIdx.x, img = blockIdx.x;
    const int wave = t >> 6, lane = t & 63;
    const char* gimg = (const char*)x + (size_t)img * IMG_BYTES;
    float* __restrict__ o = out + (size_t)img * 49152;

    // issue quarters 0,1,2 into slots 0,1,2 (3 ops of 1 KB per wave per quarter)
#pragma unroll
    for (int q = 0; q < 3; ++q)
#pragma unroll
        for (int j = 0; j < 3; ++j)
            gload16(gimg + q * QTR_BYTES + (wave * 3 + j) * 1024 + lane * 16,
                    stage + q * QTR_BYTES + (wave * 3 + j) * 1024);

    uint32 pk[16];
    float m1 = 3.4e38f, m2 = 3.4e38f;          // min(L), min(100-L)

    __syncthreads();                           // q0-q2 landed (vmcnt drain + barrier)
    do_quarter((const float*)stage, t, 0, pk, m1, m2);
    __syncthreads();                           // all waves done reading slot 0
#pragma unroll
    for (int j = 0; j < 3; ++j)                // stage q3 into slot 0
        gload16(gimg + 3 * QTR_BYTES + (wave * 3 + j) * 1024 + lane * 16,
                stage + (wave * 3 + j) * 1024);
    do_quarter((const float*)(stage + QTR_BYTES), t, 1, pk, m1, m2);
    do_quarter((const float*)(stage + 2 * QTR_BYTES), t, 2, pk, m1, m2);
    __syncthreads();                           // q3 landed
    do_quarter((const float*)stage, t, 3, pk, m1, m2);

    // wave reduce (64 lanes), then 16-wave LDS reduce
#pragma unroll
    for (int m = 32; m; m >>= 1) {
        m1 = fminf(m1, __shfl_xor(m1, m, 64));
        m2 = fminf(m2, __shfl_xor(m2, m, 64));
    }
    if ((t & 63) == 0) { sm[(t >> 6) * 2] = m1; sm[(t >> 6) * 2 + 1] = m2; }
    __syncthreads();
    float Lmin = 3.4e38f, M2 = 3.4e38f;
#pragma unroll
    for (int i = 0; i < 16; ++i) {             // broadcast reads, conflict-free
        Lmin = fminf(Lmin, sm[2 * i]);
        M2   = fminf(M2,   sm[2 * i + 1]);
    }
    const float s = 1.0f / ((100.0f - M2) - Lmin);

#pragma unroll
    for (int k = 0; k < 16; ++k) {
        const int q = k >> 2, i = k & 3;
        const uint32 v = pk[k];
        float* w = o + 3 * ((q << 12) + (i << 10) + t);   // 12 B/lane, merged dwordx3
        w[0] = ((float)__builtin_bit_cast(_Float16, (unsigned short)(v >> 16)) - Lmin) * s;
        w[1] = (float)(v & 255u) * (1.0f / 255.0f);
        w[2] = (float)((v >> 8) & 255u) * (1.0f / 255.0f);
    }
}

// ---- fallback: round-1 fused kernel (68 us, verified) ----
__global__ __launch_bounds__(1024) void k_fb(const float* __restrict__ x,
                                             float* __restrict__ out) {
    const int img = blockIdx.x, t = threadIdx.x;
    const size_t base = (size_t)img * 49152;
    const float* __restrict__ in = x + base;
    float* __restrict__ o = out + base;

    uint32 pk[16];
    float m1 = 3.4e38f, m2 = 3.4e38f;
#pragma unroll
    for (int i = 0; i < 16; ++i) {
        const int p = t + (i << 10);
        const float* q = in + 3 * p;
        float L, a01, b01;
        px(q[0], q[1], q[2], L, a01, b01);
        m1 = fminf(m1, L);
        m2 = fminf(m2, 100.0f - L);
        pk[i] = packpx(L, a01, b01);
    }
#pragma unroll
    for (int m = 32; m; m >>= 1) {
        m1 = fminf(m1, __shfl_xor(m1, m, 64));
        m2 = fminf(m2, __shfl_xor(m2, m, 64));
    }
    __shared__ float sm[32];
    if ((t & 63) == 0) { sm[(t >> 6) * 2] = m1; sm[(t >> 6) * 2 + 1] = m2; }
    __syncthreads();
    float Lmin = 3.4e38f, M2 = 3.4e38f;
#pragma unroll
    for (int i = 0; i < 16; ++i) {
        Lmin = fminf(Lmin, sm[2 * i]);
        M2   = fminf(M2,   sm[2 * i + 1]);
    }
    const float s = 1.0f / ((100.0f - M2) - Lmin);
#pragma unroll
    for (int i = 0; i < 16; ++i) {
        const int p = t + (i << 10);
        const uint32 v = pk[i];
        float* q = o + 3 * p;
        q[0] = ((float)__builtin_bit_cast(_Float16, (unsigned short)(v >> 16)) - Lmin) * s;
        q[1] = (float)(v & 255u) * (1.0f / 255.0f);
        q[2] = (float)((v >> 8) & 255u) * (1.0f / 255.0f);
    }
}

extern "C" void kernel_launch(void* const* d_in, const int* in_sizes, int n_in,
                              void* d_out, int out_size, void* d_ws, size_t ws_size,
                              hipStream_t stream) {
    (void)in_sizes; (void)n_in; (void)out_size; (void)d_ws; (void)ws_size;
    const float* x = (const float*)d_in[0];
    float* out = (float*)d_out;

    static int attr_ok = -1;                   // host-side one-time; capture-safe
    if (attr_ok < 0) {
        attr_ok = (hipFuncSetAttribute((const void*)k_gl,
                                       hipFuncAttributeMaxDynamicSharedMemorySize,
                                       3 * QTR_BYTES) == hipSuccess) ? 1 : 0;
    }
    if (attr_ok) {
        k_gl<<<512, 1024, 3 * QTR_BYTES, stream>>>(x, out);
    } else {
        k_fb<<<512, 1024, 0, stream>>>(x, out);
    }
}